// Round 8
// baseline (157.515 us; speedup 1.0000x reference)
//
#include <hip/hip_runtime.h>
#include <math.h>

#define B_ 2
#define S_ 2048
#define M_ 1024
#define R_ 64
#define N_ 16
#define NC 64          // s-chunks
#define CH 32          // S_/NC
#define MT 128         // m per scan block

// ws float offsets
#define DT_OFF  0                    // 4,194,304
#define AGG_OFF 4194304              // 4,194,304  (g,h)x16n per (b,c,m)
#define BP_OFF  8388608              // 65,536
#define CP_OFF  8454144              // 65,536
// total 8,519,680 floats = 34.1 MiB

// ============================================================================
// dt = clip(softplus(delta @ Wdt^T + bdt), 1e-6, 10); grid (4, 512) x 256
// W row in 64 VGPRs (standalone kernel => no register-sharing with other code)
// ============================================================================
__global__ __launch_bounds__(256) void k_dt(const float* __restrict__ delta,
                                            const float* __restrict__ Wdt,
                                            const float* __restrict__ bdt,
                                            float* __restrict__ dt) {
    int m    = blockIdx.x * 256 + threadIdx.x;         // 0..1023
    int row0 = blockIdx.y * 8;                         // bs base
    float w[R_];
    const float4* W4 = reinterpret_cast<const float4*>(Wdt + (size_t)m * R_);
#pragma unroll
    for (int i = 0; i < R_ / 4; ++i) {
        float4 v = W4[i];
        w[4*i] = v.x; w[4*i+1] = v.y; w[4*i+2] = v.z; w[4*i+3] = v.w;
    }
    float bias = bdt[m];
#pragma unroll 1
    for (int r = 0; r < 8; ++r) {
        int bs = row0 + r;
        const float* dr = delta + (size_t)bs * R_;     // wave-uniform -> s_load
        float acc = bias;
#pragma unroll
        for (int k = 0; k < R_; ++k) acc = fmaf(dr[k], w[k], acc);
        float sp = fmaxf(acc, 0.f) + log1pf(expf(-fabsf(acc)));
        sp = fminf(fmaxf(sp, 1e-6f), 10.0f);
        dt[(size_t)bs * M_ + m] = sp;
    }
}

// ============================================================================
// B/C projection, full-K per block: 512 blocks x 8 rows, 256 threads.
// thread: n = tid&15, khalf = (tid>>4)&1, r = tid>>5. Final write (no partials).
// ============================================================================
__global__ __launch_bounds__(256) void k_bc(const float* __restrict__ u,
                                            const float* __restrict__ Bw,
                                            const float* __restrict__ Cw,
                                            float* __restrict__ Bp,
                                            float* __restrict__ Cp) {
    __shared__ float uLds[8 * 1024];                   // 32 KiB
    const int r0 = blockIdx.x * 8;
    const int tid = threadIdx.x;
    for (int i = tid; i < 2048; i += 256) {            // 2048 float4
        *reinterpret_cast<float4*>(&uLds[i * 4]) =
            *reinterpret_cast<const float4*>(&u[(size_t)r0 * M_ + i * 4]);
    }
    __syncthreads();
    const int n  = tid & 15;
    const int kh = (tid >> 4) & 1;
    const int r  = tid >> 5;
    const int k0 = kh * 512;
    const float4* u4  = reinterpret_cast<const float4*>(uLds + r * 1024 + k0);
    const float4* wB4 = reinterpret_cast<const float4*>(Bw + (size_t)n * M_ + k0);
    const float4* wC4 = reinterpret_cast<const float4*>(Cw + (size_t)n * M_ + k0);
    float accB = 0.f, accC = 0.f;
#pragma unroll 4
    for (int k4 = 0; k4 < 128; ++k4) {
        float4 uv = u4[k4], wb = wB4[k4], wc = wC4[k4];
        accB = fmaf(uv.x, wb.x, accB);
        accB = fmaf(uv.y, wb.y, accB);
        accB = fmaf(uv.z, wb.z, accB);
        accB = fmaf(uv.w, wb.w, accB);
        accC = fmaf(uv.x, wc.x, accC);
        accC = fmaf(uv.y, wc.y, accC);
        accC = fmaf(uv.z, wc.z, accC);
        accC = fmaf(uv.w, wc.w, accC);
    }
    accB += __shfl_xor(accB, 16, 64);                  // combine k-halves
    accC += __shfl_xor(accC, 16, 64);
    if (kh == 0) {
        Bp[(size_t)(r0 + r) * N_ + n] = accB;
        Cp[(size_t)(r0 + r) * N_ + n] = accC;
    }
}

// ============================================================================
// pass1: per-chunk (g = prod e^a, h) from (1,0), 16 n-states per thread.
// grid (8, NC, B_), 128 threads (thread = one m). B row is wave-uniform ->
// scalar loads, zero LDS traffic for B. Agg[((b*NC+c)*1024+m)*32 + n*2+{g,h}]
// ============================================================================
__global__ __launch_bounds__(128) void k_pass1(const float* __restrict__ dt,
                                               const float* __restrict__ u,
                                               const float* __restrict__ Bp,
                                               const float* __restrict__ A_log,
                                               float* __restrict__ Agg) {
    __shared__ float ldsDt[CH * MT], ldsU[CH * MT];    // 32 KiB
    const int m0 = blockIdx.x * MT, c = blockIdx.y, b = blockIdx.z;
    const int s0 = c * CH;
    const int tid = threadIdx.x;
    for (int i = tid; i < 1024; i += 128) {            // float4 staging
        int s = i >> 5, mq = (i & 31) * 4;
        size_t off = ((size_t)(b * S_ + s0 + s)) * M_ + m0 + mq;
        *reinterpret_cast<float4*>(&ldsDt[s * MT + mq]) = *reinterpret_cast<const float4*>(&dt[off]);
        *reinterpret_cast<float4*>(&ldsU [s * MT + mq]) = *reinterpret_cast<const float4*>(&u[off]);
    }
    const int m = m0 + tid;
    float Aa[16], g[16], h[16];
#pragma unroll
    for (int j = 0; j < 16; ++j) {
        float a = -expf(A_log[(size_t)j * M_ + m]);
        Aa[j] = fminf(fmaxf(a, -10.f), -1e-6f);
        g[j] = 1.f; h[j] = 0.f;
    }
    __syncthreads();
#pragma unroll 1
    for (int s = 0; s < CH; ++s) {
        float dtv = ldsDt[s * MT + tid];
        float uv  = ldsU [s * MT + tid];
        float du  = dtv * uv;
        const float4* Br = reinterpret_cast<const float4*>(Bp + (size_t)(b * S_ + s0 + s) * N_);
        float4 b0 = Br[0], b1 = Br[1], b2 = Br[2], b3 = Br[3];   // uniform -> s_load
        float bb[16] = {b0.x,b0.y,b0.z,b0.w, b1.x,b1.y,b1.z,b1.w,
                        b2.x,b2.y,b2.z,b2.w, b3.x,b3.y,b3.z,b3.w};
#pragma unroll
        for (int j = 0; j < 16; ++j) {
            float ea = __expf(dtv * Aa[j]);
            h[j] = fmaf(ea, h[j], g[j] * (du * bb[j]));
            g[j] *= ea;
        }
    }
    float* dst = Agg + ((size_t)(b * NC + c) * M_ + m) * 32;
#pragma unroll
    for (int j = 0; j < 8; ++j) {                      // 8 x float4, coalesced
        *reinterpret_cast<float4*>(dst + j * 4) =
            make_float4(g[2*j], h[2*j], g[2*j+1], h[2*j+1]);
    }
}

// ============================================================================
// pass2: per-(b,m,n) exclusive fold over NC chunk aggs, in place, 8-batched
// loads. 32768 chains; grid 512 x 64.
// ============================================================================
__global__ __launch_bounds__(64) void k_pass2(float* __restrict__ Agg) {
    const int idx = blockIdx.x * 64 + threadIdx.x;     // 0..32767
    const int n = idx & 15;
    const int m = (idx >> 4) & 1023;
    const int b = idx >> 14;
    float* p = Agg + ((size_t)(b * NC) * M_ + m) * 32 + n * 2;
    float grun = 1.f, hrun = 0.f;
#pragma unroll 1
    for (int c0 = 0; c0 < NC; c0 += 8) {
        float2 v[8];
#pragma unroll
        for (int t = 0; t < 8; ++t)
            v[t] = *reinterpret_cast<const float2*>(p + (size_t)(c0 + t) * (M_ * 32));
#pragma unroll
        for (int t = 0; t < 8; ++t) {
            *reinterpret_cast<float2*>(p + (size_t)(c0 + t) * (M_ * 32)) =
                make_float2(grun, hrun);
            hrun = fmaf(v[t].x, hrun, grun * v[t].y);
            grun *= v[t].x;
        }
    }
}

// ============================================================================
// pass3: load (g,h) init, run recurrence, y = sum_n h*C in-thread, write out.
// grid (8, NC, B_), 128 threads. B and C rows via wave-uniform scalar loads.
// ============================================================================
__global__ __launch_bounds__(128) void k_pass3(const float* __restrict__ dt,
                                               const float* __restrict__ u,
                                               const float* __restrict__ Bp,
                                               const float* __restrict__ Cp,
                                               const float* __restrict__ A_log,
                                               const float* __restrict__ Dskip,
                                               const float* __restrict__ Agg,
                                               float* __restrict__ out) {
    __shared__ float ldsDt[CH * MT], ldsU[CH * MT];    // 32 KiB
    const int m0 = blockIdx.x * MT, c = blockIdx.y, b = blockIdx.z;
    const int s0 = c * CH;
    const int tid = threadIdx.x;
    for (int i = tid; i < 1024; i += 128) {
        int s = i >> 5, mq = (i & 31) * 4;
        size_t off = ((size_t)(b * S_ + s0 + s)) * M_ + m0 + mq;
        *reinterpret_cast<float4*>(&ldsDt[s * MT + mq]) = *reinterpret_cast<const float4*>(&dt[off]);
        *reinterpret_cast<float4*>(&ldsU [s * MT + mq]) = *reinterpret_cast<const float4*>(&u[off]);
    }
    const int m = m0 + tid;
    float Aa[16], g[16], h[16];
    {
        const float4* ini = reinterpret_cast<const float4*>(
            Agg + ((size_t)(b * NC + c) * M_ + m) * 32);
#pragma unroll
        for (int j = 0; j < 8; ++j) {
            float4 q = ini[j];
            g[2*j]   = q.x; h[2*j]   = q.y;
            g[2*j+1] = q.z; h[2*j+1] = q.w;
        }
    }
#pragma unroll
    for (int j = 0; j < 16; ++j) {
        float a = -expf(A_log[(size_t)j * M_ + m]);
        Aa[j] = fminf(fmaxf(a, -10.f), -1e-6f);
    }
    const float Dm = Dskip[m];
    __syncthreads();
#pragma unroll 1
    for (int s = 0; s < CH; ++s) {
        float dtv = ldsDt[s * MT + tid];
        float uv  = ldsU [s * MT + tid];
        float du  = dtv * uv;
        const float4* Br = reinterpret_cast<const float4*>(Bp + (size_t)(b * S_ + s0 + s) * N_);
        const float4* Cr = reinterpret_cast<const float4*>(Cp + (size_t)(b * S_ + s0 + s) * N_);
        float4 b0 = Br[0], b1 = Br[1], b2 = Br[2], b3 = Br[3];   // uniform -> s_load
        float4 c0v = Cr[0], c1v = Cr[1], c2v = Cr[2], c3v = Cr[3];
        float bb[16] = {b0.x,b0.y,b0.z,b0.w, b1.x,b1.y,b1.z,b1.w,
                        b2.x,b2.y,b2.z,b2.w, b3.x,b3.y,b3.z,b3.w};
        float cc[16] = {c0v.x,c0v.y,c0v.z,c0v.w, c1v.x,c1v.y,c1v.z,c1v.w,
                        c2v.x,c2v.y,c2v.z,c2v.w, c3v.x,c3v.y,c3v.z,c3v.w};
        float y = 0.f;
#pragma unroll
        for (int j = 0; j < 16; ++j) {
            float ea = __expf(dtv * Aa[j]);
            h[j] = fmaf(ea, h[j], g[j] * (du * bb[j]));
            g[j] *= ea;
            y = fmaf(h[j], cc[j], y);
        }
        float o = y + uv * Dm;
        o = fminf(fmaxf(o, -10000.f), 10000.f);
        out[((size_t)(b * S_ + s0 + s)) * M_ + m] = o;
    }
}

extern "C" void kernel_launch(void* const* d_in, const int* in_sizes, int n_in,
                              void* d_out, int out_size, void* d_ws, size_t ws_size,
                              hipStream_t stream) {
    const float* u     = (const float*)d_in[0];
    const float* delta = (const float*)d_in[1];
    const float* Wdt   = (const float*)d_in[2];
    const float* bdt   = (const float*)d_in[3];
    const float* A_log = (const float*)d_in[4];
    const float* Dski  = (const float*)d_in[5];
    const float* Bw    = (const float*)d_in[6];
    const float* Cw    = (const float*)d_in[7];
    float* out = (float*)d_out;
    float* ws  = (float*)d_ws;

    float* dt  = ws + DT_OFF;
    float* Agg = ws + AGG_OFF;
    float* Bp  = ws + BP_OFF;
    float* Cp  = ws + CP_OFF;

    k_dt<<<dim3(4, 512), 256, 0, stream>>>(delta, Wdt, bdt, dt);
    k_bc<<<512, 256, 0, stream>>>(u, Bw, Cw, Bp, Cp);
    k_pass1<<<dim3(8, NC, B_), 128, 0, stream>>>(dt, u, Bp, A_log, Agg);
    k_pass2<<<512, 64, 0, stream>>>(Agg);
    k_pass3<<<dim3(8, NC, B_), 128, 0, stream>>>(dt, u, Bp, Cp, A_log, Dski, Agg, out);
}

// Round 9
// 114.488 us; speedup vs baseline: 1.3758x; 1.3758x over previous
//
#include <hip/hip_runtime.h>
#include <math.h>

#define B_ 2
#define S_ 2048
#define M_ 1024
#define R_ 64
#define N_ 16
#define NC 64          // s-chunks
#define CH 32          // S_/NC
#define LOG2E 1.44269504088896f

// ws float offsets
#define DT_OFF  0                    // 4,194,304
#define AGG_OFF 4194304              // 4,194,304  (g,h)x16n per (b,c,m)
#define BWT_OFF 8388608              // 16,384
#define CWT_OFF 8404992              // 16,384
#define PB_OFF  8421376              // 131,072 (2 k-split partials, B)
#define PC_OFF  8552448              // 131,072 (C)
// total 8,683,520 floats = 34.7 MiB

// ============================================================================
// dt = clip(softplus(delta @ Wdt^T + bdt), 1e-6, 10); grid (4, 512) x 256.
// Embeds the Bw/Cw transpose (8 elements per block; consumed by NEXT kernel).
// ============================================================================
__global__ __launch_bounds__(256) void k_dt(const float* __restrict__ delta,
                                            const float* __restrict__ Wdt,
                                            const float* __restrict__ bdt,
                                            const float* __restrict__ Bw,
                                            const float* __restrict__ Cw,
                                            float* __restrict__ dt,
                                            float* __restrict__ BwT,
                                            float* __restrict__ CwT) {
    int bid = blockIdx.y * 4 + blockIdx.x;             // 0..2047
    if (threadIdx.x < 8) {
        int idx = bid * 8 + threadIdx.x;               // 0..16383
        int mt = idx >> 4, nt = idx & 15;
        BwT[idx] = Bw[nt * M_ + mt];
        CwT[idx] = Cw[nt * M_ + mt];
    }
    int m    = blockIdx.x * 256 + threadIdx.x;         // 0..1023
    int row0 = blockIdx.y * 8;                         // bs base
    float w[R_];
    const float4* W4 = reinterpret_cast<const float4*>(Wdt + (size_t)m * R_);
#pragma unroll
    for (int i = 0; i < R_ / 4; ++i) {
        float4 v = W4[i];
        w[4*i] = v.x; w[4*i+1] = v.y; w[4*i+2] = v.z; w[4*i+3] = v.w;
    }
    float bias = bdt[m];
#pragma unroll 1
    for (int r = 0; r < 8; ++r) {
        int bs = row0 + r;
        const float* dr = delta + (size_t)bs * R_;     // wave-uniform -> s_load
        float acc = bias;
#pragma unroll
        for (int k = 0; k < R_; ++k) acc = fmaf(dr[k], w[k], acc);
        float sp = fmaxf(acc, 0.f) + log1pf(expf(-fabsf(acc)));
        sp = fminf(fmaxf(sp, 1e-6f), 10.0f);
        dt[(size_t)bs * M_ + m] = sp;
    }
}

// ============================================================================
// B/C projection, 2-way K-split partials; grid (256 row-groups, 2 k-splits).
// Coalesced: BwT/CwT[k][n] rows, 64 B contiguous per 16 lanes. (R4-proven.)
// ============================================================================
__global__ __launch_bounds__(256) void k_bc_partial(const float* __restrict__ u,
                                                    const float* __restrict__ BwT,
                                                    const float* __restrict__ CwT,
                                                    float* __restrict__ pB,
                                                    float* __restrict__ pC) {
    __shared__ float uLds[16 * 516];                   // padded: stride 516
    int r0 = blockIdx.x * 16;
    int k0 = blockIdx.y * 512;
    for (int i = threadIdx.x; i < 2048; i += 256) {
        int r = i >> 7, kq = i & 127;
        float4 v = *reinterpret_cast<const float4*>(&u[(size_t)(r0 + r) * M_ + k0 + kq * 4]);
        *reinterpret_cast<float4*>(&uLds[r * 516 + kq * 4]) = v;
    }
    __syncthreads();
    int r = threadIdx.x >> 4, n = threadIdx.x & 15;
    const float4* u4 = reinterpret_cast<const float4*>(uLds + r * 516);
    float accB = 0.f, accC = 0.f;
#pragma unroll 4
    for (int k4 = 0; k4 < 128; ++k4) {
        float4 uv = u4[k4];
        int kb = k0 + k4 * 4;
        accB = fmaf(uv.x, BwT[(kb+0)*16 + n], accB);
        accB = fmaf(uv.y, BwT[(kb+1)*16 + n], accB);
        accB = fmaf(uv.z, BwT[(kb+2)*16 + n], accB);
        accB = fmaf(uv.w, BwT[(kb+3)*16 + n], accB);
        accC = fmaf(uv.x, CwT[(kb+0)*16 + n], accC);
        accC = fmaf(uv.y, CwT[(kb+1)*16 + n], accC);
        accC = fmaf(uv.z, CwT[(kb+2)*16 + n], accC);
        accC = fmaf(uv.w, CwT[(kb+3)*16 + n], accC);
    }
    size_t o = (size_t)blockIdx.y * 65536 + (size_t)(r0 + r) * 16 + n;
    pB[o] = accB;
    pC[o] = accC;
}

// ============================================================================
// pass1: per-chunk aggregates via S-form (exact reference chunk math):
//   T = sum dt;  S[j] = sum du*b[j]*exp2(-dt*Aa2[j]);
//   g_c = exp2(Aa2[j]*T);  h_c = g_c*S[j].
// grid (16, NC, B_), 256 thr, 4 n/thread, 32 waves/CU.
// Agg layout: Agg[((b*NC+c)*M_+m)*32 + n*2 + {0:g,1:h}]
// ============================================================================
__global__ __launch_bounds__(256, 8) void k_pass1(const float* __restrict__ dt,
                                                  const float* __restrict__ u,
                                                  const float* __restrict__ pB,
                                                  const float* __restrict__ A_log,
                                                  float* __restrict__ Agg) {
    __shared__ float ldsDt[CH * 64], ldsU[CH * 64], ldsB[CH * 16];
    const int m0 = blockIdx.x * 64, c = blockIdx.y, b = blockIdx.z;
    const int s0 = c * CH;
    const int tid = threadIdx.x;
    for (int i = tid; i < 512; i += 256) {             // float4 staging
        int s = i >> 4, mq = (i & 15) * 4;
        size_t off = ((size_t)(b * S_ + s0 + s)) * M_ + m0 + mq;
        *reinterpret_cast<float4*>(&ldsDt[s * 64 + mq]) = *reinterpret_cast<const float4*>(&dt[off]);
        *reinterpret_cast<float4*>(&ldsU [s * 64 + mq]) = *reinterpret_cast<const float4*>(&u[off]);
    }
    {
        size_t base = (size_t)(b * S_ + s0) * N_;
        for (int i = tid; i < CH * 16; i += 256)
            ldsB[i] = pB[base + i] + pB[65536 + base + i];
    }
    __syncthreads();
    const int lane = tid & 63, wave = tid >> 6;
    const int ml = wave * 16 + (lane & 15);
    const int m  = m0 + ml;
    const int n0 = (lane >> 4) * 4;
    float Aa2[4], S[4] = {0,0,0,0};
    float T = 0.f;
#pragma unroll
    for (int j = 0; j < 4; ++j) {
        float a = -expf(A_log[(size_t)(n0 + j) * M_ + m]);
        Aa2[j] = fminf(fmaxf(a, -10.f), -1e-6f) * LOG2E;
    }
    for (int s = 0; s < CH; ++s) {
        float dtv = ldsDt[s * 64 + ml];
        float uv  = ldsU [s * 64 + ml];
        float du  = dtv * uv;
        T += dtv;
        float4 bv = *reinterpret_cast<const float4*>(&ldsB[s * 16 + n0]);
        float bb[4] = {bv.x, bv.y, bv.z, bv.w};
#pragma unroll
        for (int j = 0; j < 4; ++j) {
            float em = exp2f(-dtv * Aa2[j]);           // e^{-a}
            S[j] = fmaf(du * bb[j], em, S[j]);
        }
    }
    float g[4], h[4];
#pragma unroll
    for (int j = 0; j < 4; ++j) {
        g[j] = exp2f(Aa2[j] * T);
        h[j] = g[j] * S[j];
    }
    float* dst = Agg + ((size_t)(b * NC + c) * M_ + m) * 32 + n0 * 2;
    *reinterpret_cast<float4*>(dst)     = make_float4(g[0], h[0], g[1], h[1]);
    *reinterpret_cast<float4*>(dst + 4) = make_float4(g[2], h[2], g[3], h[3]);
}

// ============================================================================
// pass2: per-(b,m,n) exclusive fold over NC chunk aggs, in place, 8-batched.
// 32768 chains; grid 512 x 64.
// ============================================================================
__global__ __launch_bounds__(64) void k_pass2(float* __restrict__ Agg) {
    const int idx = blockIdx.x * 64 + threadIdx.x;     // 0..32767
    const int n = idx & 15;
    const int m = (idx >> 4) & 1023;
    const int b = idx >> 14;
    float* p = Agg + ((size_t)(b * NC) * M_ + m) * 32 + n * 2;
    float grun = 1.f, hrun = 0.f;
#pragma unroll 1
    for (int c0 = 0; c0 < NC; c0 += 8) {
        float2 v[8];
#pragma unroll
        for (int t = 0; t < 8; ++t)
            v[t] = *reinterpret_cast<const float2*>(p + (size_t)(c0 + t) * (M_ * 32));
#pragma unroll
        for (int t = 0; t < 8; ++t) {
            *reinterpret_cast<float2*>(p + (size_t)(c0 + t) * (M_ * 32)) =
                make_float2(grun, hrun);
            hrun = fmaf(v[t].x, hrun, grun * v[t].y);
            grun *= v[t].x;
        }
    }
}

// ============================================================================
// pass3: (g,h) from inits; ea=exp2(dt*Aa2); h = ea*h + g*du*b; g *= ea;
// y = sum_n h*C via shfl. grid (16, NC, B_), 256 thr, 4 n/thread, 32 waves/CU.
// ============================================================================
__global__ __launch_bounds__(256, 8) void k_pass3(const float* __restrict__ dt,
                                                  const float* __restrict__ u,
                                                  const float* __restrict__ pB,
                                                  const float* __restrict__ pC,
                                                  const float* __restrict__ A_log,
                                                  const float* __restrict__ Dskip,
                                                  const float* __restrict__ Agg,
                                                  float* __restrict__ out) {
    __shared__ float ldsDt[CH * 64], ldsU[CH * 64], ldsB[CH * 16], ldsC[CH * 16];
    const int m0 = blockIdx.x * 64, c = blockIdx.y, b = blockIdx.z;
    const int s0 = c * CH;
    const int tid = threadIdx.x;
    for (int i = tid; i < 512; i += 256) {
        int s = i >> 4, mq = (i & 15) * 4;
        size_t off = ((size_t)(b * S_ + s0 + s)) * M_ + m0 + mq;
        *reinterpret_cast<float4*>(&ldsDt[s * 64 + mq]) = *reinterpret_cast<const float4*>(&dt[off]);
        *reinterpret_cast<float4*>(&ldsU [s * 64 + mq]) = *reinterpret_cast<const float4*>(&u[off]);
    }
    {
        size_t base = (size_t)(b * S_ + s0) * N_;
        for (int i = tid; i < CH * 16; i += 256) {
            ldsB[i] = pB[base + i] + pB[65536 + base + i];
            ldsC[i] = pC[base + i] + pC[65536 + base + i];
        }
    }
    __syncthreads();
    const int lane = tid & 63, wave = tid >> 6;
    const int ml = wave * 16 + (lane & 15);
    const int m  = m0 + ml;
    const int ng = lane >> 4, n0 = ng * 4;
    float Aa2[4], g[4], h[4];
    {
        const float* ini = Agg + ((size_t)(b * NC + c) * M_ + m) * 32 + n0 * 2;
        float4 q0 = *reinterpret_cast<const float4*>(ini);
        float4 q1 = *reinterpret_cast<const float4*>(ini + 4);
        g[0] = q0.x; h[0] = q0.y; g[1] = q0.z; h[1] = q0.w;
        g[2] = q1.x; h[2] = q1.y; g[3] = q1.z; h[3] = q1.w;
    }
#pragma unroll
    for (int j = 0; j < 4; ++j) {
        float a = -expf(A_log[(size_t)(n0 + j) * M_ + m]);
        Aa2[j] = fminf(fmaxf(a, -10.f), -1e-6f) * LOG2E;
    }
    const float Dm = Dskip[m];
    for (int s = 0; s < CH; ++s) {
        float dtv = ldsDt[s * 64 + ml];
        float uv  = ldsU [s * 64 + ml];
        float du  = dtv * uv;
        float4 bv = *reinterpret_cast<const float4*>(&ldsB[s * 16 + n0]);
        float4 cv = *reinterpret_cast<const float4*>(&ldsC[s * 16 + n0]);
        float bb[4] = {bv.x, bv.y, bv.z, bv.w};
        float cc[4] = {cv.x, cv.y, cv.z, cv.w};
        float y = 0.f;
#pragma unroll
        for (int j = 0; j < 4; ++j) {
            float ea = exp2f(dtv * Aa2[j]);
            h[j] = fmaf(ea, h[j], g[j] * (du * bb[j]));
            g[j] *= ea;
            y = fmaf(h[j], cc[j], y);
        }
        y += __shfl_xor(y, 16, 64);
        y += __shfl_xor(y, 32, 64);
        if (ng == 0) {
            float o = y + uv * Dm;
            o = fminf(fmaxf(o, -10000.f), 10000.f);
            out[((size_t)(b * S_ + s0 + s)) * M_ + m] = o;
        }
    }
}

extern "C" void kernel_launch(void* const* d_in, const int* in_sizes, int n_in,
                              void* d_out, int out_size, void* d_ws, size_t ws_size,
                              hipStream_t stream) {
    const float* u     = (const float*)d_in[0];
    const float* delta = (const float*)d_in[1];
    const float* Wdt   = (const float*)d_in[2];
    const float* bdt   = (const float*)d_in[3];
    const float* A_log = (const float*)d_in[4];
    const float* Dski  = (const float*)d_in[5];
    const float* Bw    = (const float*)d_in[6];
    const float* Cw    = (const float*)d_in[7];
    float* out = (float*)d_out;
    float* ws  = (float*)d_ws;

    float* dt  = ws + DT_OFF;
    float* Agg = ws + AGG_OFF;
    float* BwT = ws + BWT_OFF;
    float* CwT = ws + CWT_OFF;
    float* pB  = ws + PB_OFF;
    float* pC  = ws + PC_OFF;

    k_dt<<<dim3(4, 512), 256, 0, stream>>>(delta, Wdt, bdt, Bw, Cw, dt, BwT, CwT);
    k_bc_partial<<<dim3(256, 2), 256, 0, stream>>>(u, BwT, CwT, pB, pC);
    k_pass1<<<dim3(16, NC, B_), 256, 0, stream>>>(dt, u, pB, A_log, Agg);
    k_pass2<<<512, 64, 0, stream>>>(Agg);
    k_pass3<<<dim3(16, NC, B_), 256, 0, stream>>>(dt, u, pB, pC, A_log, Dski, Agg, out);
}